// Round 2
// baseline (1917.294 us; speedup 1.0000x reference)
//
#include <hip/hip_runtime.h>
#include <stdint.h>

// ---- problem constants ----
#define HID   3072
#define LSEQ  2304
#define NH    24
#define HD    128
#define N1    21504   // 3*HID + MLP
#define QKVW  9216    // 3*HID
#define X2W   15360   // HID + MLP

typedef __bf16 bf16x8 __attribute__((ext_vector_type(8)));
typedef unsigned short u16x8 __attribute__((ext_vector_type(8)));
typedef float f32x4 __attribute__((ext_vector_type(4)));

#define MFMA(a,b,c) __builtin_amdgcn_mfma_f32_16x16x32_bf16((a),(b),(c),0,0,0)

// async global->LDS, 16B per lane; LDS dest = wave-uniform base + lane*16
#define GLOAD_LDS16(g, l) __builtin_amdgcn_global_load_lds( \
    (const __attribute__((address_space(1))) unsigned int*)(g), \
    (__attribute__((address_space(3))) unsigned int*)(l), 16, 0, 0)

__device__ __forceinline__ unsigned short f2b(float f){
  unsigned int u = __builtin_bit_cast(unsigned int, f);
  u += 0x7fffu + ((u >> 16) & 1u);   // RTNE
  return (unsigned short)(u >> 16);
}
__device__ __forceinline__ float b2f(unsigned short b){
  return __builtin_bit_cast(float, ((unsigned int)b) << 16);
}
__device__ __forceinline__ unsigned int pk2(float lo, float hi){
  return (unsigned int)f2b(lo) | ((unsigned int)f2b(hi) << 16);
}

// ---------------- silu(temb) ----------------
__global__ void silu_k(const float* __restrict__ temb, float* __restrict__ st){
  int i = blockIdx.x*256 + threadIdx.x;
  if (i < HID){ float x = temb[i]; st[i] = x / (1.f + __expf(-x)); }
}

// ---------------- emb = silu(temb) @ ada_w + ada_b ----------------
__global__ __launch_bounds__(256) void ada_k(const float* __restrict__ st,
                                             const float* __restrict__ aw,
                                             const float* __restrict__ ab,
                                             float* __restrict__ emb){
  int c = threadIdx.x & 31, g = threadIdx.x >> 5;
  int col = blockIdx.x*32 + c;
  float acc = 0.f;
  for (int k = g; k < HID; k += 8)
    acc += st[k] * aw[(size_t)k*QKVW + col];
  __shared__ float part[256];
  part[threadIdx.x] = acc;
  __syncthreads();
  if (threadIdx.x < 32){
    float s = 0.f;
    #pragma unroll
    for (int j = 0; j < 8; ++j) s += part[j*32 + threadIdx.x];
    int cc = blockIdx.x*32 + threadIdx.x;
    emb[cc] = s + ab[cc];
  }
}

// ---------------- LayerNorm + (1+scale)/shift modulation -> bf16 ----------------
__global__ __launch_bounds__(256) void ln_k(const float* __restrict__ hs,
                                            const float* __restrict__ emb,
                                            unsigned short* __restrict__ nx){
  int l = blockIdx.x, t = threadIdx.x;
  const float* row = hs + (size_t)l*HID;
  float x[12], s = 0.f, ss = 0.f;
  #pragma unroll
  for (int i = 0; i < 12; ++i){ x[i] = row[t + i*256]; s += x[i]; ss += x[i]*x[i]; }
  #pragma unroll
  for (int off = 32; off; off >>= 1){ s += __shfl_xor(s, off); ss += __shfl_xor(ss, off); }
  __shared__ float red[8];
  int w = t >> 6, lane = t & 63;
  if (!lane){ red[w] = s; red[4+w] = ss; }
  __syncthreads();
  s = red[0]+red[1]+red[2]+red[3];
  ss = red[4]+red[5]+red[6]+red[7];
  float mu = s * (1.f/HID);
  float var = ss * (1.f/HID) - mu*mu;
  float rstd = rsqrtf(var + 1e-6f);
  #pragma unroll
  for (int i = 0; i < 12; ++i){
    int c = t + i*256;
    float v = (x[i]-mu)*rstd*(1.f + emb[HID + c]) + emb[c];
    nx[(size_t)l*HID + c] = f2b(v);
  }
}

// ---------------- weight convert+transpose: W fp32 [K rows][ldw cols] -> WT bf16 [n][K] ----------------
__global__ __launch_bounds__(256) void tconv_k(const float* __restrict__ W,
                                               unsigned short* __restrict__ WT,
                                               int ldw, int K){
  __shared__ unsigned short Ls[64*66];
  int k0 = blockIdx.x*64, n0 = blockIdx.y*64;
  int t = threadIdx.x;
  #pragma unroll
  for (int p = 0; p < 4; ++p){
    int idx = p*256 + t, row = idx >> 4, c4 = idx & 15;
    float4 f = *(const float4*)(W + (size_t)(k0+row)*ldw + n0 + c4*4);
    *(unsigned int*)&Ls[row*66 + c4*4]     = pk2(f.x, f.y);
    *(unsigned int*)&Ls[row*66 + c4*4 + 2] = pk2(f.z, f.w);
  }
  __syncthreads();
  #pragma unroll
  for (int p = 0; p < 2; ++p){
    int idx = p*256 + t, n = idx >> 3, ch = idx & 7;
    u16x8 r;
    #pragma unroll
    for (int j = 0; j < 8; ++j) r[j] = Ls[(ch*8 + j)*66 + n];
    *(uint4*)(WT + (size_t)(n0+n)*K + k0 + ch*8) = __builtin_bit_cast(uint4, r);
  }
}

// ================= 256x256 8-wave counted-vmcnt GEMM (lin1) =================
// C = A(bf16 [M][K]) @ BT(bf16 [N][K])^T + bias
// BK=32, 4 LDS slots, prefetch distance 3 tiles, steady-state vmcnt(8).
// EPI=1: qkv cols (bf16 -> o16[gm*QKVW + gn]); EPI=3: gelu -> o16[gm*X2W + HID + gn]
template<int EPI>
__global__ __launch_bounds__(512, 2)
void gemm256_k(const unsigned short* __restrict__ A, const unsigned short* __restrict__ BT,
               const float* __restrict__ bias, int K, int NT,
               unsigned short* __restrict__ o16)
{
  __shared__ __align__(16) unsigned short As[4][256*32];
  __shared__ __align__(16) unsigned short Bs[4][256*32];
  const int t = threadIdx.x;
  const int m0 = blockIdx.y * 256, n0 = blockIdx.x * 256;
  const int w = t >> 6, lane = t & 63, quad = lane >> 4, l16 = lane & 15;
  const int wr = w >> 2, wc = w & 3;          // wave grid 2(M) x 4(N); per-wave 128x64

  const unsigned short* aSrc[2];
  const unsigned short* bSrc[2];
  #pragma unroll
  for (int p = 0; p < 2; ++p){
    int lin = p*512 + t;
    int row = lin >> 2;                        // 0..255
    int ch  = (lin & 3) ^ ((row >> 1) & 3);    // swizzled 16B chunk within the 64B row
    aSrc[p] = A  + (size_t)(m0 + row)*K + ch*8;
    bSrc[p] = BT + (size_t)(n0 + row)*K + ch*8;
  }
  const int ldsOff0 = w*512;
  const int ldsOff1 = 4096 + w*512;

#define STAGE_A(slot, pf) do{ \
    GLOAD_LDS16(aSrc[0] + (size_t)(pf)*32, &As[slot][ldsOff0]); \
    GLOAD_LDS16(aSrc[1] + (size_t)(pf)*32, &As[slot][ldsOff1]); }while(0)
#define STAGE_B(slot, pf) do{ \
    GLOAD_LDS16(bSrc[0] + (size_t)(pf)*32, &Bs[slot][ldsOff0]); \
    GLOAD_LDS16(bSrc[1] + (size_t)(pf)*32, &Bs[slot][ldsOff1]); }while(0)

  const int kSwz  = (quad ^ ((l16 >> 1) & 3)) * 8;
  const int aBase = (wr*128 + l16)*32 + kSwz;
  const int bBase = (wc*64  + l16)*32 + kSwz;

  f32x4 acc[8][4];
  #pragma unroll
  for (int i = 0; i < 8; ++i)
    #pragma unroll
    for (int j = 0; j < 4; ++j) acc[i][j] = (f32x4){0.f,0.f,0.f,0.f};

  STAGE_A(0, 0); STAGE_B(0, 0);
  STAGE_A(1, 1); STAGE_B(1, 1);
  STAGE_A(2, 2); STAGE_B(2, 2);
  asm volatile("s_waitcnt vmcnt(8)" ::: "memory");
  __builtin_amdgcn_sched_barrier(0);
  __builtin_amdgcn_s_barrier();

  for (int kt = 0; kt < NT; ++kt){
    const int slot  = kt & 3;
    const int wslot = (kt + 3) & 3;
    const int pf    = (kt + 3 < NT) ? (kt + 3) : (NT - 1);
    bf16x8 af[4], bf[4];

    // ---- phase 0 ----
    STAGE_A(wslot, pf);
    #pragma unroll
    for (int i = 0; i < 4; ++i)
      af[i] = __builtin_bit_cast(bf16x8, *(const uint4*)&As[slot][aBase + i*512]);
    #pragma unroll
    for (int i = 0; i < 4; ++i)
      bf[i] = __builtin_bit_cast(bf16x8, *(const uint4*)&Bs[slot][bBase + i*512]);
    __builtin_amdgcn_s_barrier();
    asm volatile("s_waitcnt lgkmcnt(0)" ::: "memory");
    __builtin_amdgcn_sched_barrier(0);
    __builtin_amdgcn_s_setprio(1);
    #pragma unroll
    for (int mi = 0; mi < 4; ++mi)
      #pragma unroll
      for (int ni = 0; ni < 4; ++ni)
        acc[mi][ni] = MFMA(af[mi], bf[ni], acc[mi][ni]);
    __builtin_amdgcn_s_setprio(0);

    // ---- phase 1 ----
    STAGE_B(wslot, pf);
    #pragma unroll
    for (int i = 0; i < 4; ++i)
      af[i] = __builtin_bit_cast(bf16x8, *(const uint4*)&As[slot][aBase + 2048 + i*512]);
    __builtin_amdgcn_s_barrier();
    asm volatile("s_waitcnt lgkmcnt(0)" ::: "memory");
    __builtin_amdgcn_sched_barrier(0);
    __builtin_amdgcn_s_setprio(1);
    #pragma unroll
    for (int mi = 0; mi < 4; ++mi)
      #pragma unroll
      for (int ni = 0; ni < 4; ++ni)
        acc[4+mi][ni] = MFMA(af[mi], bf[ni], acc[4+mi][ni]);
    __builtin_amdgcn_s_setprio(0);
    asm volatile("s_waitcnt vmcnt(8)" ::: "memory");
    __builtin_amdgcn_sched_barrier(0);
    __builtin_amdgcn_s_barrier();
  }
#undef STAGE_A
#undef STAGE_B

  asm volatile("s_waitcnt vmcnt(0)" ::: "memory");

  #pragma unroll
  for (int mi = 0; mi < 8; ++mi){
    #pragma unroll
    for (int ni = 0; ni < 4; ++ni){
      const int gn = n0 + wc*64 + ni*16 + l16;
      const float bs = bias[gn];
      #pragma unroll
      for (int r = 0; r < 4; ++r){
        const int gm = m0 + wr*128 + mi*16 + quad*4 + r;
        float v = acc[mi][ni][r] + bs;
        if (EPI == 1){
          o16[(size_t)gm*QKVW + gn] = f2b(v);
        } else {
          float e = __expf(1.5957691216057308f*(v + 0.044715f*v*v*v));
          float th = 1.f - 2.f/(e + 1.f);
          o16[(size_t)gm*X2W + HID + gn] = f2b(0.5f*v*(1.f + th));
        }
      }
    }
  }
}

// ================= 128(M)x256(N) 8-wave counted-vmcnt GEMM (lin2) =================
// Same schedule as gemm256_k; per-wave 64x64 (acc[4][4]); 3 loads/thread/tile ->
// steady-state vmcnt(6). LDS 96KB (A 4x8KB + B 4x16KB). Grid 12x18 = 216 blocks.
// Epilogue: of[gm*HID+gn] = hid[...] + v*gate
__global__ __launch_bounds__(512, 2)
void gemm256n_k(const unsigned short* __restrict__ A, const unsigned short* __restrict__ BT,
                const float* __restrict__ bias, int K, int NT,
                float* __restrict__ of, const float* __restrict__ hid,
                const float* __restrict__ emb)
{
  __shared__ __align__(16) unsigned short As[4][128*32];
  __shared__ __align__(16) unsigned short Bs[4][256*32];
  const int t = threadIdx.x;
  const int m0 = blockIdx.y * 128, n0 = blockIdx.x * 256;
  const int w = t >> 6, lane = t & 63, quad = lane >> 4, l16 = lane & 15;
  const int wr = w >> 2, wc = w & 3;          // wave grid 2(M) x 4(N); per-wave 64x64

  const unsigned short* aSrc;
  { int row = t >> 2, ch = (t & 3) ^ ((row >> 1) & 3);
    aSrc = A + (size_t)(m0 + row)*K + ch*8; }
  const unsigned short* bSrc[2];
  #pragma unroll
  for (int p = 0; p < 2; ++p){
    int lin = p*512 + t, row = lin >> 2, ch = (lin & 3) ^ ((row >> 1) & 3);
    bSrc[p] = BT + (size_t)(n0 + row)*K + ch*8;
  }
  const int aOff  = w*512;
  const int bOff0 = w*512, bOff1 = 4096 + w*512;

#define STAGE(slot, pf) do{ \
    GLOAD_LDS16(aSrc    + (size_t)(pf)*32, &As[slot][aOff]); \
    GLOAD_LDS16(bSrc[0] + (size_t)(pf)*32, &Bs[slot][bOff0]); \
    GLOAD_LDS16(bSrc[1] + (size_t)(pf)*32, &Bs[slot][bOff1]); }while(0)

  const int kSwz  = (quad ^ ((l16 >> 1) & 3)) * 8;
  const int aBase = (wr*64 + l16)*32 + kSwz;
  const int bBase = (wc*64 + l16)*32 + kSwz;

  f32x4 acc[4][4];
  #pragma unroll
  for (int i = 0; i < 4; ++i)
    #pragma unroll
    for (int j = 0; j < 4; ++j) acc[i][j] = (f32x4){0.f,0.f,0.f,0.f};

  STAGE(0, 0); STAGE(1, 1); STAGE(2, 2);
  asm volatile("s_waitcnt vmcnt(6)" ::: "memory");
  __builtin_amdgcn_sched_barrier(0);
  __builtin_amdgcn_s_barrier();

  for (int kt = 0; kt < NT; ++kt){
    const int slot  = kt & 3;
    const int wslot = (kt + 3) & 3;
    const int pf    = (kt + 3 < NT) ? (kt + 3) : (NT - 1);
    bf16x8 af[4], bf[4];

    STAGE(wslot, pf);
    #pragma unroll
    for (int i = 0; i < 4; ++i)
      af[i] = __builtin_bit_cast(bf16x8, *(const uint4*)&As[slot][aBase + i*512]);
    #pragma unroll
    for (int i = 0; i < 4; ++i)
      bf[i] = __builtin_bit_cast(bf16x8, *(const uint4*)&Bs[slot][bBase + i*512]);
    __builtin_amdgcn_s_barrier();
    asm volatile("s_waitcnt lgkmcnt(0)" ::: "memory");
    __builtin_amdgcn_sched_barrier(0);
    __builtin_amdgcn_s_setprio(1);
    #pragma unroll
    for (int mi = 0; mi < 4; ++mi)
      #pragma unroll
      for (int ni = 0; ni < 4; ++ni)
        acc[mi][ni] = MFMA(af[mi], bf[ni], acc[mi][ni]);
    __builtin_amdgcn_s_setprio(0);
    asm volatile("s_waitcnt vmcnt(6)" ::: "memory");
    __builtin_amdgcn_sched_barrier(0);
    __builtin_amdgcn_s_barrier();
  }
#undef STAGE

  asm volatile("s_waitcnt vmcnt(0)" ::: "memory");

  #pragma unroll
  for (int mi = 0; mi < 4; ++mi){
    #pragma unroll
    for (int ni = 0; ni < 4; ++ni){
      const int gn = n0 + wc*64 + ni*16 + l16;
      const float bs = bias[gn];
      #pragma unroll
      for (int r = 0; r < 4; ++r){
        const int gm = m0 + wr*64 + mi*16 + quad*4 + r;
        float v = acc[mi][ni][r] + bs;
        of[(size_t)gm*HID + gn] = hid[(size_t)gm*HID + gn] + v * emb[2*HID + gn];
      }
    }
  }
}

// ---------------- q/k RMSNorm + RoPE (in place on qkv), fold 1/sqrt(HD) into q ----------------
__global__ __launch_bounds__(256) void qknorm_k(unsigned short* __restrict__ qkv,
                                                const float* __restrict__ qn,
                                                const float* __restrict__ kn,
                                                const float* __restrict__ cosp,
                                                const float* __restrict__ sinp,
                                                const int* __restrict__ txtp){
  int img = LSEQ - txtp[0];
  int rid = blockIdx.x*4 + (threadIdx.x >> 6);
  int lane = threadIdx.x & 63;
  int which = rid / (NH*LSEQ);
  int rem   = rid % (NH*LSEQ);
  int h = rem / LSEQ, l = rem % LSEQ;
  unsigned short* p = qkv + (size_t)l*QKVW + which*HID + h*HD + lane*2;
  unsigned int both = *(const unsigned int*)p;
  float x0 = b2f((unsigned short)(both & 0xffffu));
  float x1 = b2f((unsigned short)(both >> 16));
  float ss = x0*x0 + x1*x1;
  #pragma unroll
  for (int off = 32; off; off >>= 1) ss += __shfl_xor(ss, off);
  float r = rsqrtf(ss*(1.f/HD) + 1e-6f);
  const float* wv = which ? kn : qn;
  float y0 = x0*r*wv[lane*2], y1 = x1*r*wv[lane*2+1];
  if (l < img){
    float c0 = cosp[l*HD + lane*2], c1 = cosp[l*HD + lane*2 + 1];
    float s0 = sinp[l*HD + lane*2], s1 = sinp[l*HD + lane*2 + 1];
    float t0 = y0*c0 - y1*s0;
    float t1 = y1*c1 + y0*s1;
    y0 = t0; y1 = t1;
  }
  if (which == 0){ y0 *= 0.08838834764831845f; y1 *= 0.08838834764831845f; }
  *(unsigned int*)p = pk2(y0, y1);
}

// ---------------- V transpose: qkv v-part [l][h*128+d] -> vT[h][d][l] ----------------
__global__ __launch_bounds__(256) void vtrans_k(const unsigned short* __restrict__ qkv,
                                                unsigned short* __restrict__ vT){
  __shared__ __align__(16) unsigned short Ls[64*136];
  int h = blockIdx.y, m0 = blockIdx.x*64, t = threadIdx.x;
  #pragma unroll
  for (int p = 0; p < 4; ++p){
    int lin = p*256 + t, m = lin >> 4, ch = lin & 15;
    *(uint4*)&Ls[m*136 + ch*8] =
      *(const uint4*)(qkv + (size_t)(m0+m)*QKVW + 2*HID + h*HD + ch*8);
  }
  __syncthreads();
  #pragma unroll
  for (int p = 0; p < 4; ++p){
    int lin = p*256 + t, d = lin >> 3, ch = lin & 7;
    u16x8 r;
    #pragma unroll
    for (int j = 0; j < 8; ++j) r[j] = Ls[(ch*8 + j)*136 + d];
    *(uint4*)(vT + (size_t)h*HD*LSEQ + (size_t)d*LSEQ + m0 + ch*8) =
      __builtin_bit_cast(uint4, r);
  }
}

// ---------------- flash attention: per (head, 64 q), online softmax over 32-key chunks ----------------
__global__ __launch_bounds__(256)
void attn_k(const unsigned short* __restrict__ qkv,
            const unsigned short* __restrict__ vT,
            unsigned short* __restrict__ x2)
{
  __shared__ __align__(16) unsigned short Ks[32*136];   // [key][d]
  __shared__ __align__(16) unsigned short Vt[128*40];   // [d][m]
  __shared__ __align__(16) unsigned short Ps[4*16*40];  // per-wave P round-trip
  const int h = blockIdx.y, qb = blockIdx.x*64;
  const int t = threadIdx.x, w = t >> 6, lane = t & 63, quad = lane >> 4, l16 = lane & 15;

  bf16x8 aq[4];
  {
    const unsigned short* qp = qkv + (size_t)(qb + w*16 + l16)*QKVW + h*HD;
    #pragma unroll
    for (int dt = 0; dt < 4; ++dt)
      aq[dt] = __builtin_bit_cast(bf16x8, *(const uint4*)(qp + dt*32 + quad*8));
  }
  f32x4 o[8];
  #pragma unroll
  for (int i = 0; i < 8; ++i) o[i] = (f32x4){0.f,0.f,0.f,0.f};
  float mr[4] = {-1e30f,-1e30f,-1e30f,-1e30f};
  float lr[4] = {0.f,0.f,0.f,0.f};

  const unsigned short* kb = qkv + HID + h*HD;
  const unsigned short* vb = vT + (size_t)h*HD*LSEQ;
  unsigned short* pw = &Ps[w*16*40];

  for (int m0 = 0; m0 < LSEQ; m0 += 32){
    __syncthreads();
    #pragma unroll
    for (int p = 0; p < 2; ++p){
      int lin = p*256 + t, kr = lin >> 4, ch = lin & 15;
      *(uint4*)&Ks[kr*136 + ch*8] = *(const uint4*)(kb + (size_t)(m0+kr)*QKVW + ch*8);
    }
    #pragma unroll
    for (int p = 0; p < 2; ++p){
      int lin = p*256 + t, d = lin >> 2, ch = lin & 3;
      *(uint4*)&Vt[d*40 + ch*8] = *(const uint4*)(vb + (size_t)d*LSEQ + m0 + ch*8);
    }
    __syncthreads();

    f32x4 s0 = (f32x4){0.f,0.f,0.f,0.f}, s1 = s0;
    __builtin_amdgcn_s_setprio(1);
    #pragma unroll
    for (int dt = 0; dt < 4; ++dt){
      bf16x8 k0 = __builtin_bit_cast(bf16x8, *(const uint4*)&Ks[l16*136 + dt*32 + quad*8]);
      bf16x8 k1 = __builtin_bit_cast(bf16x8, *(const uint4*)&Ks[(16+l16)*136 + dt*32 + quad*8]);
      s0 = MFMA(aq[dt], k0, s0);
      s1 = MFMA(aq[dt], k1, s1);
    }
    __builtin_amdgcn_s_setprio(0);
    #pragma unroll
    for (int r = 0; r < 4; ++r){
      float mx = fmaxf(s0[r], s1[r]);
      mx = fmaxf(mx, __shfl_xor(mx, 1));
      mx = fmaxf(mx, __shfl_xor(mx, 2));
      mx = fmaxf(mx, __shfl_xor(mx, 4));
      mx = fmaxf(mx, __shfl_xor(mx, 8));
      float mn = fmaxf(mr[r], mx);
      float al = __expf(mr[r] - mn);
      float p0 = __expf(s0[r] - mn), p1 = __expf(s1[r] - mn);
      float rs = p0 + p1;
      rs += __shfl_xor(rs, 1);
      rs += __shfl_xor(rs, 2);
      rs += __shfl_xor(rs, 4);
      rs += __shfl_xor(rs, 8);
      lr[r] = lr[r]*al + rs;
      mr[r] = mn;
      #pragma unroll
      for (int i = 0; i < 8; ++i) o[i][r] *= al;
      int q = quad*4 + r;
      pw[q*40 + l16]      = f2b(p0);
      pw[q*40 + 16 + l16] = f2b(p1);
    }
    bf16x8 pa = __builtin_bit_cast(bf16x8, *(const uint4*)&pw[l16*40 + quad*8]);
    __builtin_amdgcn_s_setprio(1);
    #pragma unroll
    for (int i = 0; i < 8; ++i){
      bf16x8 vv = __builtin_bit_cast(bf16x8, *(const uint4*)&Vt[(i*16 + l16)*40 + quad*8]);
      o[i] = MFMA(pa, vv, o[i]);
    }
    __builtin_amdgcn_s_setprio(0);
  }
  #pragma unroll
  for (int i = 0; i < 8; ++i){
    #pragma unroll
    for (int r = 0; r < 4; ++r){
      int q = qb + w*16 + quad*4 + r;
      x2[(size_t)q*X2W + h*HD + i*16 + l16] = f2b(o[i][r] / lr[r]);
    }
  }
}

// ---------------- launch ----------------
extern "C" void kernel_launch(void* const* d_in, const int* in_sizes, int n_in,
                              void* d_out, int out_size, void* d_ws, size_t ws_size,
                              hipStream_t stream) {
  const float* hs     = (const float*)d_in[0];
  const float* temb   = (const float*)d_in[1];
  const float* cosp   = (const float*)d_in[2];
  const float* sinp   = (const float*)d_in[3];
  const float* ada_w  = (const float*)d_in[4];
  const float* ada_b  = (const float*)d_in[5];
  const float* lin1_w = (const float*)d_in[6];
  const float* lin1_b = (const float*)d_in[7];
  const float* lin2_w = (const float*)d_in[8];
  const float* lin2_b = (const float*)d_in[9];
  const float* qn     = (const float*)d_in[10];
  const float* kn     = (const float*)d_in[11];
  const int*   txt    = (const int*)d_in[12];
  float* out = (float*)d_out;

  char* ws = (char*)d_ws;
  float*          st  = (float*)ws;                          // 12,288 B
  float*          emb = (float*)(ws + 12288);                // 36,864 B
  unsigned short* nx  = (unsigned short*)(ws + 49152);       // 14,155,776 B
  unsigned short* qkv = (unsigned short*)(ws + 14204928);    // 42,467,328 B
  unsigned short* x2  = (unsigned short*)(ws + 56672256);    // 70,778,880 B
  unsigned short* vT  = (unsigned short*)(ws + 127451136);   // 14,155,776 B
  unsigned short* wt  = (unsigned short*)(ws + 141606912);   // 94,371,840 B -> end 235,978,752

  silu_k<<<12, 256, 0, stream>>>(temb, st);
  ada_k<<<288, 256, 0, stream>>>(st, ada_w, ada_b, emb);
  ln_k<<<LSEQ, 256, 0, stream>>>(hs, emb, nx);

  // lin1, qkv half: convert cols 0..9215 then 256^2 8-wave GEMM
  tconv_k<<<dim3(HID/64, QKVW/64), 256, 0, stream>>>(lin1_w, wt, N1, HID);
  gemm256_k<1><<<dim3(QKVW/256, LSEQ/256), 512, 0, stream>>>(nx, wt, lin1_b, HID, HID/32, qkv);
  // lin1, mlp half: convert cols 9216..21503 then GEMM (gelu epilogue into x2)
  tconv_k<<<dim3(HID/64, (N1-QKVW)/64), 256, 0, stream>>>(lin1_w + QKVW, wt, N1, HID);
  gemm256_k<3><<<dim3((N1-QKVW)/256, LSEQ/256), 512, 0, stream>>>(nx, wt, lin1_b + QKVW, HID, HID/32, x2);

  qknorm_k<<<(2*NH*LSEQ)/4, 256, 0, stream>>>(qkv, qn, kn, cosp, sinp, txt);
  vtrans_k<<<dim3(LSEQ/64, NH), 256, 0, stream>>>(qkv, vT);
  attn_k<<<dim3(LSEQ/64, NH), 256, 0, stream>>>(qkv, vT, x2);

  // lin2: convert [15360][3072] -> [3072][15360] then 128x256 8-wave GEMM
  tconv_k<<<dim3(X2W/64, HID/64), 256, 0, stream>>>(lin2_w, wt, HID, X2W);
  gemm256n_k<<<dim3(HID/256, LSEQ/128), 512, 0, stream>>>(x2, wt, lin2_b, X2W, X2W/32,
                                                          out, hs, emb);
}

// Round 3
// 1806.734 us; speedup vs baseline: 1.0612x; 1.0612x over previous
//
#include <hip/hip_runtime.h>
#include <stdint.h>

// ---- problem constants ----
#define HID   3072
#define LSEQ  2304
#define NH    24
#define HD    128
#define N1    21504   // 3*HID + MLP
#define QKVW  9216    // 3*HID
#define X2W   15360   // HID + MLP

typedef __bf16 bf16x8 __attribute__((ext_vector_type(8)));
typedef unsigned short u16x8 __attribute__((ext_vector_type(8)));
typedef float f32x4 __attribute__((ext_vector_type(4)));

#define MFMA(a,b,c) __builtin_amdgcn_mfma_f32_16x16x32_bf16((a),(b),(c),0,0,0)

// async global->LDS, 16B per lane; LDS dest = wave-uniform base + lane*16
#define GLOAD_LDS16(g, l) __builtin_amdgcn_global_load_lds( \
    (const __attribute__((address_space(1))) unsigned int*)(g), \
    (__attribute__((address_space(3))) unsigned int*)(l), 16, 0, 0)

__device__ __forceinline__ unsigned short f2b(float f){
  unsigned int u = __builtin_bit_cast(unsigned int, f);
  u += 0x7fffu + ((u >> 16) & 1u);   // RTNE
  return (unsigned short)(u >> 16);
}
__device__ __forceinline__ float b2f(unsigned short b){
  return __builtin_bit_cast(float, ((unsigned int)b) << 16);
}
__device__ __forceinline__ unsigned int pk2(float lo, float hi){
  return (unsigned int)f2b(lo) | ((unsigned int)f2b(hi) << 16);
}
__device__ __forceinline__ bf16x8 ldsv(const unsigned short* p){
  return __builtin_bit_cast(bf16x8, *(const uint4*)p);
}

// ---------------- silu(temb) ----------------
__global__ void silu_k(const float* __restrict__ temb, float* __restrict__ st){
  int i = blockIdx.x*256 + threadIdx.x;
  if (i < HID){ float x = temb[i]; st[i] = x / (1.f + __expf(-x)); }
}

// ---------------- emb = silu(temb) @ ada_w + ada_b ----------------
__global__ __launch_bounds__(256) void ada_k(const float* __restrict__ st,
                                             const float* __restrict__ aw,
                                             const float* __restrict__ ab,
                                             float* __restrict__ emb){
  int c = threadIdx.x & 31, g = threadIdx.x >> 5;
  int col = blockIdx.x*32 + c;
  float acc = 0.f;
  for (int k = g; k < HID; k += 8)
    acc += st[k] * aw[(size_t)k*QKVW + col];
  __shared__ float part[256];
  part[threadIdx.x] = acc;
  __syncthreads();
  if (threadIdx.x < 32){
    float s = 0.f;
    #pragma unroll
    for (int j = 0; j < 8; ++j) s += part[j*32 + threadIdx.x];
    int cc = blockIdx.x*32 + threadIdx.x;
    emb[cc] = s + ab[cc];
  }
}

// ---------------- LayerNorm + (1+scale)/shift modulation -> bf16 ----------------
__global__ __launch_bounds__(256) void ln_k(const float* __restrict__ hs,
                                            const float* __restrict__ emb,
                                            unsigned short* __restrict__ nx){
  int l = blockIdx.x, t = threadIdx.x;
  const float* row = hs + (size_t)l*HID;
  float x[12], s = 0.f, ss = 0.f;
  #pragma unroll
  for (int i = 0; i < 12; ++i){ x[i] = row[t + i*256]; s += x[i]; ss += x[i]*x[i]; }
  #pragma unroll
  for (int off = 32; off; off >>= 1){ s += __shfl_xor(s, off); ss += __shfl_xor(ss, off); }
  __shared__ float red[8];
  int w = t >> 6, lane = t & 63;
  if (!lane){ red[w] = s; red[4+w] = ss; }
  __syncthreads();
  s = red[0]+red[1]+red[2]+red[3];
  ss = red[4]+red[5]+red[6]+red[7];
  float mu = s * (1.f/HID);
  float var = ss * (1.f/HID) - mu*mu;
  float rstd = rsqrtf(var + 1e-6f);
  #pragma unroll
  for (int i = 0; i < 12; ++i){
    int c = t + i*256;
    float v = (x[i]-mu)*rstd*(1.f + emb[HID + c]) + emb[c];
    nx[(size_t)l*HID + c] = f2b(v);
  }
}

// ---------------- weight convert+transpose: W fp32 [K rows][ldw cols] -> WT bf16 [n][K] ----------------
__global__ __launch_bounds__(256) void tconv_k(const float* __restrict__ W,
                                               unsigned short* __restrict__ WT,
                                               int ldw, int K){
  __shared__ unsigned short Ls[64*66];
  int k0 = blockIdx.x*64, n0 = blockIdx.y*64;
  int t = threadIdx.x;
  #pragma unroll
  for (int p = 0; p < 4; ++p){
    int idx = p*256 + t, row = idx >> 4, c4 = idx & 15;
    float4 f = *(const float4*)(W + (size_t)(k0+row)*ldw + n0 + c4*4);
    *(unsigned int*)&Ls[row*66 + c4*4]     = pk2(f.x, f.y);
    *(unsigned int*)&Ls[row*66 + c4*4 + 2] = pk2(f.z, f.w);
  }
  __syncthreads();
  #pragma unroll
  for (int p = 0; p < 2; ++p){
    int idx = p*256 + t, n = idx >> 3, ch = idx & 7;
    u16x8 r;
    #pragma unroll
    for (int j = 0; j < 8; ++j) r[j] = Ls[(ch*8 + j)*66 + n];
    *(uint4*)(WT + (size_t)(n0+n)*K + k0 + ch*8) = __builtin_bit_cast(uint4, r);
  }
}

// ================= lin1: 256x256 8-wave phased BK=64 counted-vmcnt GEMM =================
// C = A(bf16 [M][K]) @ BT(bf16 [N][K])^T + bias ; fused runtime epilogue:
//   gn < 9216 -> qkv bf16 ; gn >= 9216 -> gelu -> x2 (block-uniform branch).
// 2 LDS buffers (A,B each 2x256x64), 4 phases/K-tile, stage kt+2 overlapped with
// phase-3 MFMA, vmcnt(8) once per K-tile (never 0 in loop).
// LDS row = 64 bf16 = 128B, 8 chunks of 16B; swizzle: chunk ^= (row&7), both sides.
__global__ __launch_bounds__(512, 2)
void gemm8p1_k(const unsigned short* __restrict__ A, const unsigned short* __restrict__ BT,
               const float* __restrict__ bias, int K, int NT,
               unsigned short* __restrict__ qo, unsigned short* __restrict__ xo)
{
  __shared__ __align__(16) unsigned short As[2][256*64];
  __shared__ __align__(16) unsigned short Bs[2][256*64];
  const int t = threadIdx.x;
  const int m0 = blockIdx.y * 256, n0 = blockIdx.x * 256;
  const int w = t >> 6, lane = t & 63, quad = lane >> 4, l16 = lane & 15;
  const int wr = w >> 2, wc = w & 3;     // wave grid 2(M) x 4(N); per-wave 128x64

  // staging: pass p covers rows 64p..64p+63; per-thread row r0=t>>3, pre-swizzled chunk
  const int r0  = t >> 3;
  const int chs = (t & 7) ^ (r0 & 7);
  const unsigned short* aS = A  + (size_t)(m0 + r0)*K + chs*8;
  const unsigned short* bS = BT + (size_t)(n0 + r0)*K + chs*8;
  const int dst = t*8;                    // LDS elems, pass p adds p*4096

#define STG1(c, pf) do{ const size_t _k = (size_t)(pf)*64; \
    GLOAD_LDS16(aS + _k,                 &As[c][dst]); \
    GLOAD_LDS16(aS +  64*(size_t)K + _k, &As[c][4096  + dst]); \
    GLOAD_LDS16(aS + 128*(size_t)K + _k, &As[c][8192  + dst]); \
    GLOAD_LDS16(aS + 192*(size_t)K + _k, &As[c][12288 + dst]); \
    GLOAD_LDS16(bS + _k,                 &Bs[c][dst]); \
    GLOAD_LDS16(bS +  64*(size_t)K + _k, &Bs[c][4096  + dst]); \
    GLOAD_LDS16(bS + 128*(size_t)K + _k, &Bs[c][8192  + dst]); \
    GLOAD_LDS16(bS + 192*(size_t)K + _k, &Bs[c][12288 + dst]); }while(0)

  // fragment read addressing (swizzled): row&7 == l16&7 for all frag rows
  const int sz = l16 & 7;
  const int aR = (wr*128 + l16)*64;
  const int bR = (wc*64  + l16)*64;
  const int c0 = (quad ^ sz)*8;          // kk=0 chunk (elem offset in row)
  const int c1 = ((4 + quad) ^ sz)*8;    // kk=1

  f32x4 acc[8][4];
  #pragma unroll
  for (int i = 0; i < 8; ++i)
    #pragma unroll
    for (int j = 0; j < 4; ++j) acc[i][j] = (f32x4){0.f,0.f,0.f,0.f};

  STG1(0, 0); STG1(1, 1);
  asm volatile("s_waitcnt vmcnt(8)" ::: "memory");
  __builtin_amdgcn_sched_barrier(0);
  __builtin_amdgcn_s_barrier();

  for (int kt = 0; kt < NT; ++kt){
    const int c  = kt & 1;
    const int pf = (kt + 2 < NT) ? (kt + 2) : (NT - 1);   // clamped -> flat vmcnt ledger
    const unsigned short* Ac = As[c];
    const unsigned short* Bc = Bs[c];
    bf16x8 af0[4][2], af1[4][2], bf[2][2];

    // ---- ph0: read A(mh0) 8 + B(nh0) 4 ; MFMA quadrant (mh0,nh0) ----
    #pragma unroll
    for (int mt = 0; mt < 4; ++mt){
      af0[mt][0] = ldsv(Ac + aR + mt*1024 + c0);
      af0[mt][1] = ldsv(Ac + aR + mt*1024 + c1);
    }
    #pragma unroll
    for (int nt = 0; nt < 2; ++nt){
      bf[nt][0] = ldsv(Bc + bR + nt*1024 + c0);
      bf[nt][1] = ldsv(Bc + bR + nt*1024 + c1);
    }
    __builtin_amdgcn_s_barrier();
    asm volatile("s_waitcnt lgkmcnt(0)" ::: "memory");
    __builtin_amdgcn_sched_barrier(0);
    __builtin_amdgcn_s_setprio(1);
    #pragma unroll
    for (int mt = 0; mt < 4; ++mt)
      #pragma unroll
      for (int nt = 0; nt < 2; ++nt){
        acc[mt][nt] = MFMA(af0[mt][0], bf[nt][0], acc[mt][nt]);
        acc[mt][nt] = MFMA(af0[mt][1], bf[nt][1], acc[mt][nt]);
      }
    __builtin_amdgcn_s_setprio(0);

    // ---- ph1: read A(mh1) 8 ; MFMA quadrant (mh1,nh0) ----
    #pragma unroll
    for (int mt = 0; mt < 4; ++mt){
      af1[mt][0] = ldsv(Ac + aR + 4096 + mt*1024 + c0);
      af1[mt][1] = ldsv(Ac + aR + 4096 + mt*1024 + c1);
    }
    __builtin_amdgcn_s_barrier();
    asm volatile("s_waitcnt lgkmcnt(0)" ::: "memory");
    __builtin_amdgcn_sched_barrier(0);
    __builtin_amdgcn_s_setprio(1);
    #pragma unroll
    for (int mt = 0; mt < 4; ++mt)
      #pragma unroll
      for (int nt = 0; nt < 2; ++nt){
        acc[4+mt][nt] = MFMA(af1[mt][0], bf[nt][0], acc[4+mt][nt]);
        acc[4+mt][nt] = MFMA(af1[mt][1], bf[nt][1], acc[4+mt][nt]);
      }
    __builtin_amdgcn_s_setprio(0);

    // ---- ph2: read B(nh1) 4 ; MFMA quadrant (mh1,nh1) ----
    #pragma unroll
    for (int nt = 0; nt < 2; ++nt){
      bf[nt][0] = ldsv(Bc + bR + 2048 + nt*1024 + c0);
      bf[nt][1] = ldsv(Bc + bR + 2048 + nt*1024 + c1);
    }
    __builtin_amdgcn_s_barrier();
    asm volatile("s_waitcnt lgkmcnt(0)" ::: "memory");
    __builtin_amdgcn_sched_barrier(0);
    __builtin_amdgcn_s_setprio(1);
    #pragma unroll
    for (int mt = 0; mt < 4; ++mt)
      #pragma unroll
      for (int nt = 0; nt < 2; ++nt){
        acc[4+mt][2+nt] = MFMA(af1[mt][0], bf[nt][0], acc[4+mt][2+nt]);
        acc[4+mt][2+nt] = MFMA(af1[mt][1], bf[nt][1], acc[4+mt][2+nt]);
      }
    __builtin_amdgcn_s_setprio(0);

    // ---- ph3: all reads of buf c done -> stage T(kt+2) into c, overlapped with
    //           MFMA quadrant (mh0,nh1); then counted vmcnt + tile barrier ----
    __builtin_amdgcn_s_barrier();
    STG1(c, pf);
    __builtin_amdgcn_s_setprio(1);
    #pragma unroll
    for (int mt = 0; mt < 4; ++mt)
      #pragma unroll
      for (int nt = 0; nt < 2; ++nt){
        acc[mt][2+nt] = MFMA(af0[mt][0], bf[nt][0], acc[mt][2+nt]);
        acc[mt][2+nt] = MFMA(af0[mt][1], bf[nt][1], acc[mt][2+nt]);
      }
    __builtin_amdgcn_s_setprio(0);
    asm volatile("s_waitcnt vmcnt(8)" ::: "memory");   // T(kt+1) landed; T(kt+2) in flight
    __builtin_amdgcn_sched_barrier(0);
    __builtin_amdgcn_s_barrier();
  }
#undef STG1

  asm volatile("s_waitcnt vmcnt(0)" ::: "memory");     // drain clamped dead loads

  // epilogue (C/D layout: col = l16, row = quad*4 + r); branch is block-uniform
  const bool isQ = (n0 < QKVW);
  #pragma unroll
  for (int mi = 0; mi < 8; ++mi){
    #pragma unroll
    for (int ni = 0; ni < 4; ++ni){
      const int gn = n0 + wc*64 + ni*16 + l16;
      const float bs = bias[gn];
      #pragma unroll
      for (int r = 0; r < 4; ++r){
        const int gm = m0 + wr*128 + mi*16 + quad*4 + r;
        float v = acc[mi][ni][r] + bs;
        if (isQ){
          qo[(size_t)gm*QKVW + gn] = f2b(v);
        } else {
          float e = __expf(1.5957691216057308f*(v + 0.044715f*v*v*v));
          float th = 1.f - 2.f/(e + 1.f);
          xo[(size_t)gm*X2W + HID + (gn - QKVW)] = f2b(0.5f*v*(1.f + th));
        }
      }
    }
  }
}

// ================= lin2: 256(M)x128(N) 8-wave phased BK=64 counted-vmcnt GEMM =================
// Wave grid 4(M) x 2(N); per-wave 64x64 (acc[4][4]). 6 loads/thread/K-tile -> vmcnt(6).
// LDS 96 KB (A 2x32KB + B 2x16KB). Grid 24x9 = 216 blocks.
// Epilogue: of[gm*HID+gn] = hid[...] + (v + bias)*gate
__global__ __launch_bounds__(512, 2)
void gemm8p2_k(const unsigned short* __restrict__ A, const unsigned short* __restrict__ BT,
               const float* __restrict__ bias, int K, int NT,
               float* __restrict__ of, const float* __restrict__ hid,
               const float* __restrict__ emb)
{
  __shared__ __align__(16) unsigned short As[2][256*64];
  __shared__ __align__(16) unsigned short Bs[2][128*64];
  const int t = threadIdx.x;
  const int m0 = blockIdx.y * 256, n0 = blockIdx.x * 128;
  const int w = t >> 6, lane = t & 63, quad = lane >> 4, l16 = lane & 15;
  const int wr = w >> 1, wc = w & 1;     // wave grid 4(M) x 2(N); per-wave 64x64

  const int r0  = t >> 3;
  const int chs = (t & 7) ^ (r0 & 7);
  const unsigned short* aS = A  + (size_t)(m0 + r0)*K + chs*8;
  const unsigned short* bS = BT + (size_t)(n0 + r0)*K + chs*8;
  const int dst = t*8;

#define STG2(c, pf) do{ const size_t _k = (size_t)(pf)*64; \
    GLOAD_LDS16(aS + _k,                 &As[c][dst]); \
    GLOAD_LDS16(aS +  64*(size_t)K + _k, &As[c][4096  + dst]); \
    GLOAD_LDS16(aS + 128*(size_t)K + _k, &As[c][8192  + dst]); \
    GLOAD_LDS16(aS + 192*(size_t)K + _k, &As[c][12288 + dst]); \
    GLOAD_LDS16(bS + _k,                 &Bs[c][dst]); \
    GLOAD_LDS16(bS +  64*(size_t)K + _k, &Bs[c][4096  + dst]); }while(0)

  const int sz = l16 & 7;
  const int aR = (wr*64 + l16)*64;
  const int bR = (wc*64 + l16)*64;
  const int c0 = (quad ^ sz)*8, c1 = ((4 + quad) ^ sz)*8;

  f32x4 acc[4][4];
  #pragma unroll
  for (int i = 0; i < 4; ++i)
    #pragma unroll
    for (int j = 0; j < 4; ++j) acc[i][j] = (f32x4){0.f,0.f,0.f,0.f};

  STG2(0, 0); STG2(1, 1);
  asm volatile("s_waitcnt vmcnt(6)" ::: "memory");
  __builtin_amdgcn_sched_barrier(0);
  __builtin_amdgcn_s_barrier();

  for (int kt = 0; kt < NT; ++kt){
    const int c  = kt & 1;
    const int pf = (kt + 2 < NT) ? (kt + 2) : (NT - 1);
    const unsigned short* Ac = As[c];
    const unsigned short* Bc = Bs[c];
    bf16x8 af[4][2], bf[2][2];

    // ---- ph0: read A all (8) + B(nh0) 4 ; 16 MFMA (nh0) ----
    #pragma unroll
    for (int mt = 0; mt < 4; ++mt){
      af[mt][0] = ldsv(Ac + aR + mt*1024 + c0);
      af[mt][1] = ldsv(Ac + aR + mt*1024 + c1);
    }
    #pragma unroll
    for (int nt = 0; nt < 2; ++nt){
      bf[nt][0] = ldsv(Bc + bR + nt*1024 + c0);
      bf[nt][1] = ldsv(Bc + bR + nt*1024 + c1);
    }
    __builtin_amdgcn_s_barrier();
    asm volatile("s_waitcnt lgkmcnt(0)" ::: "memory");
    __builtin_amdgcn_sched_barrier(0);
    __builtin_amdgcn_s_setprio(1);
    #pragma unroll
    for (int mt = 0; mt < 4; ++mt)
      #pragma unroll
      for (int nt = 0; nt < 2; ++nt){
        acc[mt][nt] = MFMA(af[mt][0], bf[nt][0], acc[mt][nt]);
        acc[mt][nt] = MFMA(af[mt][1], bf[nt][1], acc[mt][nt]);
      }
    __builtin_amdgcn_s_setprio(0);

    // ---- ph1: read B(nh1) 4 ; 8 MFMA (nh1, mt 0..1) ----
    #pragma unroll
    for (int nt = 0; nt < 2; ++nt){
      bf[nt][0] = ldsv(Bc + bR + 2048 + nt*1024 + c0);
      bf[nt][1] = ldsv(Bc + bR + 2048 + nt*1024 + c1);
    }
    __builtin_amdgcn_s_barrier();
    asm volatile("s_waitcnt lgkmcnt(0)" ::: "memory");
    __builtin_amdgcn_sched_barrier(0);
    __builtin_amdgcn_s_setprio(1);
    #pragma unroll
    for (int mt = 0; mt < 2; ++mt)
      #pragma unroll
      for (int nt = 0; nt < 2; ++nt){
        acc[mt][2+nt] = MFMA(af[mt][0], bf[nt][0], acc[mt][2+nt]);
        acc[mt][2+nt] = MFMA(af[mt][1], bf[nt][1], acc[mt][2+nt]);
      }
    __builtin_amdgcn_s_setprio(0);

    // ---- ph2: all reads of c done -> stage T(kt+2), overlapped with 8 MFMA ----
    __builtin_amdgcn_s_barrier();
    STG2(c, pf);
    __builtin_amdgcn_s_setprio(1);
    #pragma unroll
    for (int mt = 2; mt < 4; ++mt)
      #pragma unroll
      for (int nt = 0; nt < 2; ++nt){
        acc[mt][2+nt] = MFMA(af[mt][0], bf[nt][0], acc[mt][2+nt]);
        acc[mt][2+nt] = MFMA(af[mt][1], bf[nt][1], acc[mt][2+nt]);
      }
    __builtin_amdgcn_s_setprio(0);
    asm volatile("s_waitcnt vmcnt(6)" ::: "memory");
    __builtin_amdgcn_sched_barrier(0);
    __builtin_amdgcn_s_barrier();
  }
#undef STG2

  asm volatile("s_waitcnt vmcnt(0)" ::: "memory");

  #pragma unroll
  for (int mi = 0; mi < 4; ++mi){
    #pragma unroll
    for (int ni = 0; ni < 4; ++ni){
      const int gn = n0 + wc*64 + ni*16 + l16;
      const float bs = bias[gn];
      const float gt = emb[2*HID + gn];
      #pragma unroll
      for (int r = 0; r < 4; ++r){
        const int gm = m0 + wr*64 + mi*16 + quad*4 + r;
        float v = acc[mi][ni][r] + bs;
        of[(size_t)gm*HID + gn] = hid[(size_t)gm*HID + gn] + v * gt;
      }
    }
  }
}

// ---------------- q/k RMSNorm + RoPE (in place on qkv), fold 1/sqrt(HD) into q ----------------
__global__ __launch_bounds__(256) void qknorm_k(unsigned short* __restrict__ qkv,
                                                const float* __restrict__ qn,
                                                const float* __restrict__ kn,
                                                const float* __restrict__ cosp,
                                                const float* __restrict__ sinp,
                                                const int* __restrict__ txtp){
  int img = LSEQ - txtp[0];
  int rid = blockIdx.x*4 + (threadIdx.x >> 6);
  int lane = threadIdx.x & 63;
  int which = rid / (NH*LSEQ);
  int rem   = rid % (NH*LSEQ);
  int h = rem / LSEQ, l = rem % LSEQ;
  unsigned short* p = qkv + (size_t)l*QKVW + which*HID + h*HD + lane*2;
  unsigned int both = *(const unsigned int*)p;
  float x0 = b2f((unsigned short)(both & 0xffffu));
  float x1 = b2f((unsigned short)(both >> 16));
  float ss = x0*x0 + x1*x1;
  #pragma unroll
  for (int off = 32; off; off >>= 1) ss += __shfl_xor(ss, off);
  float r = rsqrtf(ss*(1.f/HD) + 1e-6f);
  const float* wv = which ? kn : qn;
  float y0 = x0*r*wv[lane*2], y1 = x1*r*wv[lane*2+1];
  if (l < img){
    float c0 = cosp[l*HD + lane*2], c1 = cosp[l*HD + lane*2 + 1];
    float s0 = sinp[l*HD + lane*2], s1 = sinp[l*HD + lane*2 + 1];
    float t0 = y0*c0 - y1*s0;
    float t1 = y1*c1 + y0*s1;
    y0 = t0; y1 = t1;
  }
  if (which == 0){ y0 *= 0.08838834764831845f; y1 *= 0.08838834764831845f; }
  *(unsigned int*)p = pk2(y0, y1);
}

// ---------------- V transpose: qkv v-part [l][h*128+d] -> vT[h][d][l] ----------------
__global__ __launch_bounds__(256) void vtrans_k(const unsigned short* __restrict__ qkv,
                                                unsigned short* __restrict__ vT){
  __shared__ __align__(16) unsigned short Ls[64*136];
  int h = blockIdx.y, m0 = blockIdx.x*64, t = threadIdx.x;
  #pragma unroll
  for (int p = 0; p < 4; ++p){
    int lin = p*256 + t, m = lin >> 4, ch = lin & 15;
    *(uint4*)&Ls[m*136 + ch*8] =
      *(const uint4*)(qkv + (size_t)(m0+m)*QKVW + 2*HID + h*HD + ch*8);
  }
  __syncthreads();
  #pragma unroll
  for (int p = 0; p < 4; ++p){
    int lin = p*256 + t, d = lin >> 3, ch = lin & 7;
    u16x8 r;
    #pragma unroll
    for (int j = 0; j < 8; ++j) r[j] = Ls[(ch*8 + j)*136 + d];
    *(uint4*)(vT + (size_t)h*HD*LSEQ + (size_t)d*LSEQ + m0 + ch*8) =
      __builtin_bit_cast(uint4, r);
  }
}

// ---------------- flash attention: per (head, 64 q), online softmax over 32-key chunks ----------------
__global__ __launch_bounds__(256)
void attn_k(const unsigned short* __restrict__ qkv,
            const unsigned short* __restrict__ vT,
            unsigned short* __restrict__ x2)
{
  __shared__ __align__(16) unsigned short Ks[32*136];   // [key][d]
  __shared__ __align__(16) unsigned short Vt[128*40];   // [d][m]
  __shared__ __align__(16) unsigned short Ps[4*16*40];  // per-wave P round-trip
  const int h = blockIdx.y, qb = blockIdx.x*64;
  const int t = threadIdx.x, w = t >> 6, lane = t & 63, quad = lane >> 4, l16 = lane & 15;

  bf16x8 aq[4];
  {
    const unsigned short* qp = qkv + (size_t)(qb + w*16 + l16)*QKVW + h*HD;
    #pragma unroll
    for (int dt = 0; dt < 4; ++dt)
      aq[dt] = __builtin_bit_cast(bf16x8, *(const uint4*)(qp + dt*32 + quad*8));
  }
  f32x4 o[8];
  #pragma unroll
  for (int i = 0; i < 8; ++i) o[i] = (f32x4){0.f,0.f,0.f,0.f};
  float mr[4] = {-1e30f,-1e30f,-1e30f,-1e30f};
  float lr[4] = {0.f,0.f,0.f,0.f};

  const unsigned short* kb = qkv + HID + h*HD;
  const unsigned short* vb = vT + (size_t)h*HD*LSEQ;
  unsigned short* pw = &Ps[w*16*40];

  for (int m0 = 0; m0 < LSEQ; m0 += 32){
    __syncthreads();
    #pragma unroll
    for (int p = 0; p < 2; ++p){
      int lin = p*256 + t, kr = lin >> 4, ch = lin & 15;
      *(uint4*)&Ks[kr*136 + ch*8] = *(const uint4*)(kb + (size_t)(m0+kr)*QKVW + ch*8);
    }
    #pragma unroll
    for (int p = 0; p < 2; ++p){
      int lin = p*256 + t, d = lin >> 2, ch = lin & 3;
      *(uint4*)&Vt[d*40 + ch*8] = *(const uint4*)(vb + (size_t)d*LSEQ + m0 + ch*8);
    }
    __syncthreads();

    f32x4 s0 = (f32x4){0.f,0.f,0.f,0.f}, s1 = s0;
    __builtin_amdgcn_s_setprio(1);
    #pragma unroll
    for (int dt = 0; dt < 4; ++dt){
      bf16x8 k0 = __builtin_bit_cast(bf16x8, *(const uint4*)&Ks[l16*136 + dt*32 + quad*8]);
      bf16x8 k1 = __builtin_bit_cast(bf16x8, *(const uint4*)&Ks[(16+l16)*136 + dt*32 + quad*8]);
      s0 = MFMA(aq[dt], k0, s0);
      s1 = MFMA(aq[dt], k1, s1);
    }
    __builtin_amdgcn_s_setprio(0);
    #pragma unroll
    for (int r = 0; r < 4; ++r){
      float mx = fmaxf(s0[r], s1[r]);
      mx = fmaxf(mx, __shfl_xor(mx, 1));
      mx = fmaxf(mx, __shfl_xor(mx, 2));
      mx = fmaxf(mx, __shfl_xor(mx, 4));
      mx = fmaxf(mx, __shfl_xor(mx, 8));
      float mn = fmaxf(mr[r], mx);
      float al = __expf(mr[r] - mn);
      float p0 = __expf(s0[r] - mn), p1 = __expf(s1[r] - mn);
      float rs = p0 + p1;
      rs += __shfl_xor(rs, 1);
      rs += __shfl_xor(rs, 2);
      rs += __shfl_xor(rs, 4);
      rs += __shfl_xor(rs, 8);
      lr[r] = lr[r]*al + rs;
      mr[r] = mn;
      #pragma unroll
      for (int i = 0; i < 8; ++i) o[i][r] *= al;
      int q = quad*4 + r;
      pw[q*40 + l16]      = f2b(p0);
      pw[q*40 + 16 + l16] = f2b(p1);
    }
    bf16x8 pa = __builtin_bit_cast(bf16x8, *(const uint4*)&pw[l16*40 + quad*8]);
    __builtin_amdgcn_s_setprio(1);
    #pragma unroll
    for (int i = 0; i < 8; ++i){
      bf16x8 vv = __builtin_bit_cast(bf16x8, *(const uint4*)&Vt[(i*16 + l16)*40 + quad*8]);
      o[i] = MFMA(pa, vv, o[i]);
    }
    __builtin_amdgcn_s_setprio(0);
  }
  #pragma unroll
  for (int i = 0; i < 8; ++i){
    #pragma unroll
    for (int r = 0; r < 4; ++r){
      int q = qb + w*16 + quad*4 + r;
      x2[(size_t)q*X2W + h*HD + i*16 + l16] = f2b(o[i][r] / lr[r]);
    }
  }
}

// ---------------- launch ----------------
extern "C" void kernel_launch(void* const* d_in, const int* in_sizes, int n_in,
                              void* d_out, int out_size, void* d_ws, size_t ws_size,
                              hipStream_t stream) {
  const float* hs     = (const float*)d_in[0];
  const float* temb   = (const float*)d_in[1];
  const float* cosp   = (const float*)d_in[2];
  const float* sinp   = (const float*)d_in[3];
  const float* ada_w  = (const float*)d_in[4];
  const float* ada_b  = (const float*)d_in[5];
  const float* lin1_w = (const float*)d_in[6];
  const float* lin1_b = (const float*)d_in[7];
  const float* lin2_w = (const float*)d_in[8];
  const float* lin2_b = (const float*)d_in[9];
  const float* qn     = (const float*)d_in[10];
  const float* kn     = (const float*)d_in[11];
  const int*   txt    = (const int*)d_in[12];
  float* out = (float*)d_out;

  char* ws = (char*)d_ws;
  float*          st  = (float*)ws;                          // 12,288 B
  float*          emb = (float*)(ws + 12288);                // 36,864 B
  unsigned short* nx  = (unsigned short*)(ws + 49152);       // 14,155,776 B (aliased by vT later)
  unsigned short* vT  = nx;                                  // reuse: nx dead after lin1 GEMM
  unsigned short* qkv = (unsigned short*)(ws + 14204928);    // 42,467,328 B
  unsigned short* x2  = (unsigned short*)(ws + 56672256);    // 70,778,880 B
  unsigned short* wt  = (unsigned short*)(ws + 127451136);   // 132,120,576 B -> end 259,571,712

  silu_k<<<12, 256, 0, stream>>>(temb, st);
  ada_k<<<288, 256, 0, stream>>>(st, ada_w, ada_b, emb);
  ln_k<<<LSEQ, 256, 0, stream>>>(hs, emb, nx);

  // lin1 fused: convert all 21504 cols, then one 756-block GEMM (runtime epilogue)
  tconv_k<<<dim3(HID/64, N1/64), 256, 0, stream>>>(lin1_w, wt, N1, HID);
  gemm8p1_k<<<dim3(N1/256, LSEQ/256), 512, 0, stream>>>(nx, wt, lin1_b, HID, HID/64,
                                                        qkv, x2);

  qknorm_k<<<(2*NH*LSEQ)/4, 256, 0, stream>>>(qkv, qn, kn, cosp, sinp, txt);
  vtrans_k<<<dim3(LSEQ/64, NH), 256, 0, stream>>>(qkv, vT);
  attn_k<<<dim3(LSEQ/64, NH), 256, 0, stream>>>(qkv, vT, x2);

  // lin2: convert [15360][3072] -> [3072][15360], then 256x128 phased GEMM
  tconv_k<<<dim3(X2W/64, HID/64), 256, 0, stream>>>(lin2_w, wt, HID, X2W);
  gemm8p2_k<<<dim3(HID/128, LSEQ/256), 512, 0, stream>>>(x2, wt, lin2_b, X2W, X2W/64,
                                                         out, hs, emb);
}